// Round 7
// baseline (205.866 us; speedup 1.0000x reference)
//
#include <hip/hip_runtime.h>

typedef _Float16 f16x8 __attribute__((ext_vector_type(8)));
typedef _Float16 f16x4 __attribute__((ext_vector_type(4)));
typedef __fp16 h16x2 __attribute__((ext_vector_type(2)));  // cvt_pkrtz native type
typedef float f32x4 __attribute__((ext_vector_type(4)));

#define HH 2000
#define WW 1000
#define HWSZ (HH * WW)
#define NEG_INF (-3.0e38f)

// ---- monotone float<->uint encoding for atomicMax on floats ----
// fenc never returns 0, so buckets are initialized with plain memset(0).
__device__ __forceinline__ unsigned fenc(float f) {
    unsigned u = __float_as_uint(f);
    return (u & 0x80000000u) ? ~u : (u | 0x80000000u);
}
__device__ __forceinline__ float fdec(unsigned k) {
    unsigned u = (k & 0x80000000u) ? (k & 0x7fffffffu) : ~k;
    return __uint_as_float(u);
}

__global__ void decode_buckets(unsigned* __restrict__ buck, int n) {
    int i = blockIdx.x * blockDim.x + threadIdx.x;
    if (i < n) {
        unsigned k = buck[i];
        ((float*)buck)[i] = fdec(k);
    }
}

// MFMA 16x16x32 f16 layouts (gfx950, verified: absmax ~2e-3):
//   A: lane holds A[m=lane&15][k=(lane>>4)*8+j]
//   B: lane holds B[k=(lane>>4)*8+j][n=lane&15]
//   D: lane holds D[row=(lane>>4)*4+reg][col=lane&15]
// A = weights (m = out-ch), B = activations (n = pixel).
// Biases folded in via constant-1 channel (K 9->10, 18->19, 36->37).
//
// R20 theory: R16 (8.9 waves/CU) == R19 (6.2 waves/CU) == ~80us for the same
// 64000 iterations -> throughput is wave-count-insensitive; no pipe >35%.
// The invariant serial cost: the per-iteration reduction tail (2 DEPENDENT
// ds_bpermute shuffles + waits + colmax, ~300cy after the last MFMA, nothing
// overlaps it). Fix: DEFER the reduction. Each iteration ends with 2
// fire-and-forget conflict-free b32 LDS writes of the lane's L4 partial
// (psum[row][px][q]); shuffles/maxes/atomics run ONCE per wave at the end.
// Also: back to R16's proven 16-rows/wave grid; keep 32-bit offset loads and
// the 4-accumulator dot.

__global__ __launch_bounds__(128) void mlp_max_mfma(
    const float* __restrict__ in,
    const float* __restrict__ w1, const float* __restrict__ b1,
    const float* __restrict__ w2, const float* __restrict__ b2,
    const float* __restrict__ w3, const float* __restrict__ b3,
    const float* __restrict__ w4, const float* __restrict__ b4,
    unsigned* __restrict__ rowbuck, unsigned* __restrict__ colbuck) {
    // per wave: 2 row-slots x (buf1[16][40] + buf2[16][40]) halves = 5120 B.
    // stride 40 halves = 80B keeps every b128 16B-aligned. Every byte read
    // is written earlier in the same iteration -> no zero-init needed.
    __shared__ _Float16 albuf[2][2 * 1280];
    __shared__ float psum[2][16][16][4];  // [wave][row][px][q] L4 partials

    const int tx = threadIdx.x;   // 0..63
    const int wv = threadIdx.y;   // 0..1 (independent waves)
    const int px = tx & 15;
    const int q = tx >> 4;

    _Float16* s0buf1 = &albuf[wv][0];
    _Float16* s0buf2 = &albuf[wv][640];
    _Float16* s1buf1 = &albuf[wv][1280];
    _Float16* s1buf2 = &albuf[wv][1920];

    // ---- weight A-fragments (persistent, reused every iteration) ----
    f16x8 A1[2], A2[3], A3s0[3], A3s1[3];
#pragma unroll
    for (int t = 0; t < 2; ++t) {
        const int m = t * 16 + px;
#pragma unroll
        for (int j = 0; j < 8; ++j) {
            const int k = q * 8 + j;
            float v = 0.f;
            if (m < 18) {
                if (k < 9) v = w1[m * 9 + k];
                else if (k == 9) v = b1[m];
            }
            A1[t][j] = (_Float16)v;
        }
    }
#pragma unroll
    for (int t = 0; t < 3; ++t) {
        const int m = t * 16 + px;
#pragma unroll
        for (int j = 0; j < 8; ++j) {
            const int k = q * 8 + j;
            float v = 0.f;
            if (m < 36) {
                if (k < 18) v = w2[m * 18 + k];
                else if (k == 18) v = b2[m];
            }
            A2[t][j] = (_Float16)v;
        }
    }
#pragma unroll
    for (int t = 0; t < 3; ++t) {
        const int m = t * 16 + px;
#pragma unroll
        for (int j = 0; j < 8; ++j) {
            const int k = q * 8 + j;
            float v = 0.f;
            if (m < 36 && k < 32) v = w3[m * 36 + k];
            A3s0[t][j] = (_Float16)v;
            float v2 = 0.f;
            const int k2 = 32 + k;  // slice 2: ch 32..35 real, 36 = bias
            if (m < 36) {
                if (k2 < 36) v2 = w3[m * 36 + k2];
                else if (k2 == 36) v2 = b3[m];
            }
            A3s1[t][j] = (_Float16)v2;
        }
    }

    float w4r[3][4];
#pragma unroll
    for (int t = 0; t < 3; ++t)
#pragma unroll
        for (int rg = 0; rg < 4; ++rg) {
            const int ch = t * 16 + q * 4 + rg;
            w4r[t][rg] = (ch < 36) ? w4[ch] : 0.f;
        }
    const float b4s = b4[0];

    const int col0 = blockIdx.x * 32 + wv * 16;
    const int col = col0 + px;
    const int colc = (col < WW) ? col : (WW - 1);
    const int rb = blockIdx.y * 16;

    const f32x4 zf4 = {0.f, 0.f, 0.f, 0.f};
    const h16x2 z2 = {(__fp16)0.f, (__fp16)0.f};

    union U8 { f16x8 v; h16x2 h[4]; };
    union U4 { f16x4 v; h16x2 h[2]; };

    // ---- precomputed per-lane 32-bit element offsets (loop-invariant) ----
    int off[8];
#pragma unroll
    for (int j = 0; j < 8; ++j) {
        const int c = q * 8 + j;
        off[j] = (c < 9) ? (c * HWSZ + colc) : 0;
    }

    // ---- double-buffered raw input regs: [j] for rows (r, r+1) ----
    float ca[8], cb[8], na[8], nb[8];

    auto LOAD = [&](int r, float (&v0)[8], float (&v1)[8]) {
        const float* rbase = in + (size_t)r * WW;   // wave-uniform -> SGPR base
#pragma unroll
        for (int j = 0; j < 8; ++j) {
            const int c = q * 8 + j;
            float x0 = (c == 9) ? 1.f : 0.f;  // bias ch / zero pad
            float x1 = x0;
            if (c < 9) {
                x0 = rbase[off[j]];
                x1 = rbase[off[j] + WW];   // folds into inst offset:4000
            }
            v0[j] = x0;
            v1[j] = x1;
        }
    };

    auto COMPUTE = [&](int it, const float (&v0)[8], const float (&v1)[8]) {
        // ---- pack inputs to f16 (packed RTZ cvt) ----
        U8 b0u, b1u;
#pragma unroll
        for (int j = 0; j < 4; ++j) {
            b0u.h[j] = __builtin_amdgcn_cvt_pkrtz(v0[2 * j], v0[2 * j + 1]);
            b1u.h[j] = __builtin_amdgcn_cvt_pkrtz(v1[2 * j], v1[2 * j + 1]);
        }
        const f16x8 bin0 = b0u.v;
        const f16x8 bin1 = b1u.v;

        // ---- layer 1 (bias via k=9) ----
        f32x4 D1a[2], D1b[2];
#pragma unroll
        for (int t = 0; t < 2; ++t) {
            D1a[t] = __builtin_amdgcn_mfma_f32_16x16x32_f16(A1[t], bin0, zf4, 0, 0, 0);
            D1b[t] = __builtin_amdgcn_mfma_f32_16x16x32_f16(A1[t], bin1, zf4, 0, 0, 0);
        }
#pragma unroll
        for (int t = 0; t < 2; ++t) {
            U4 h0, h1;
            h0.h[0] = __builtin_elementwise_max(
                __builtin_amdgcn_cvt_pkrtz(D1a[t][0], D1a[t][1]), z2);
            h0.h[1] = __builtin_elementwise_max(
                __builtin_amdgcn_cvt_pkrtz(D1a[t][2], D1a[t][3]), z2);
            h1.h[0] = __builtin_elementwise_max(
                __builtin_amdgcn_cvt_pkrtz(D1b[t][0], D1b[t][1]), z2);
            h1.h[1] = __builtin_elementwise_max(
                __builtin_amdgcn_cvt_pkrtz(D1b[t][2], D1b[t][3]), z2);
            if (t == 1 && q == 0) {  // ch18 = constant-1 bias channel for L2
                h0.v[2] = (_Float16)1.f;
                h1.v[2] = (_Float16)1.f;
            }
            *(f16x4*)&s0buf1[px * 40 + t * 16 + q * 4] = h0.v;
            *(f16x4*)&s1buf1[px * 40 + t * 16 + q * 4] = h1.v;
        }
        const f16x8 B2a = *(const f16x8*)&s0buf1[px * 40 + q * 8];
        const f16x8 B2b = *(const f16x8*)&s1buf1[px * 40 + q * 8];

        // ---- layer 2 (bias via k=18) ----
        f32x4 D2a[3], D2b[3];
#pragma unroll
        for (int t = 0; t < 3; ++t) {
            D2a[t] = __builtin_amdgcn_mfma_f32_16x16x32_f16(A2[t], B2a, zf4, 0, 0, 0);
            D2b[t] = __builtin_amdgcn_mfma_f32_16x16x32_f16(A2[t], B2b, zf4, 0, 0, 0);
        }
#pragma unroll
        for (int t = 0; t < 3; ++t) {
            U4 h0, h1;
            h0.h[0] = __builtin_elementwise_max(
                __builtin_amdgcn_cvt_pkrtz(D2a[t][0], D2a[t][1]), z2);
            h0.h[1] = __builtin_elementwise_max(
                __builtin_amdgcn_cvt_pkrtz(D2a[t][2], D2a[t][3]), z2);
            h1.h[0] = __builtin_elementwise_max(
                __builtin_amdgcn_cvt_pkrtz(D2b[t][0], D2b[t][1]), z2);
            h1.h[1] = __builtin_elementwise_max(
                __builtin_amdgcn_cvt_pkrtz(D2b[t][2], D2b[t][3]), z2);
            if (t < 2) {
                *(f16x4*)&s0buf2[px * 40 + t * 16 + q * 4] = h0.v;
                *(f16x4*)&s1buf2[px * 40 + t * 16 + q * 4] = h1.v;
            } else if (q == 0) {  // ch 32..35 only
                *(f16x4*)&s0buf2[px * 40 + 32] = h0.v;
                *(f16x4*)&s1buf2[px * 40 + 32] = h1.v;
            }
        }
        const f16x8 B3a0 = *(const f16x8*)&s0buf2[px * 40 + q * 8];
        const f16x8 B3b0 = *(const f16x8*)&s1buf2[px * 40 + q * 8];
        f16x8 B3a1 = {0, 0, 0, 0, 0, 0, 0, 0};
        f16x8 B3b1 = {0, 0, 0, 0, 0, 0, 0, 0};
        if (q == 0) {  // slice2: j0..3 = ch32..35, j4 = bias (=1)
            const f16x4 t0 = *(const f16x4*)&s0buf2[px * 40 + 32];
            const f16x4 t1 = *(const f16x4*)&s1buf2[px * 40 + 32];
#pragma unroll
            for (int j = 0; j < 4; ++j) { B3a1[j] = t0[j]; B3b1[j] = t1[j]; }
            B3a1[4] = (_Float16)1.f;
            B3b1[4] = (_Float16)1.f;
        }

        // ---- layer 3 (two K-slices, bias via k=36) ----
        f32x4 D3a[3], D3b[3];
#pragma unroll
        for (int t = 0; t < 3; ++t) {
            D3a[t] = __builtin_amdgcn_mfma_f32_16x16x32_f16(A3s0[t], B3a0, zf4, 0, 0, 0);
            D3a[t] = __builtin_amdgcn_mfma_f32_16x16x32_f16(A3s1[t], B3a1, D3a[t], 0, 0, 0);
            D3b[t] = __builtin_amdgcn_mfma_f32_16x16x32_f16(A3s0[t], B3b0, zf4, 0, 0, 0);
            D3b[t] = __builtin_amdgcn_mfma_f32_16x16x32_f16(A3s1[t], B3b1, D3b[t], 0, 0, 0);
        }

        // ---- layer 4: parallel 4-acc partial dot; NO reduction here ----
        float sa0 = 0.f, sa1 = 0.f, sa2 = 0.f, sa3 = 0.f;
        float sb0 = 0.f, sb1 = 0.f, sb2 = 0.f, sb3 = 0.f;
#pragma unroll
        for (int t = 0; t < 3; ++t) {
            sa0 = fmaf(w4r[t][0], fmaxf(D3a[t][0], 0.f), sa0);
            sa1 = fmaf(w4r[t][1], fmaxf(D3a[t][1], 0.f), sa1);
            sa2 = fmaf(w4r[t][2], fmaxf(D3a[t][2], 0.f), sa2);
            sa3 = fmaf(w4r[t][3], fmaxf(D3a[t][3], 0.f), sa3);
            sb0 = fmaf(w4r[t][0], fmaxf(D3b[t][0], 0.f), sb0);
            sb1 = fmaf(w4r[t][1], fmaxf(D3b[t][1], 0.f), sb1);
            sb2 = fmaf(w4r[t][2], fmaxf(D3b[t][2], 0.f), sb2);
            sb3 = fmaf(w4r[t][3], fmaxf(D3b[t][3], 0.f), sb3);
        }
        const float sa = (sa0 + sa1) + (sa2 + sa3);  // partial over this q's chs
        const float sb = (sb0 + sb1) + (sb2 + sb3);

        // fire-and-forget partial writes; words px*4+q are distinct across the
        // wave (2-way bank alias only -> free). Iteration chain ends HERE.
        psum[wv][it * 2][px][q] = sa;
        psum[wv][it * 2 + 1][px][q] = sb;
    };

    // ---- main loop: 8 iterations (16 rows), depth-1 ping-pong prefetch ----
    LOAD(rb, ca, cb);
#pragma unroll 1
    for (int it = 0; it < 8; it += 2) {
        LOAD(rb + (it + 1) * 2, na, nb);   // prefetch odd half-step
        COMPUTE(it, ca, cb);
        if (it < 6) LOAD(rb + (it + 2) * 2, ca, cb);  // prefetch next even
        COMPUTE(it + 1, na, nb);
    }

    // ---- end-of-wave deferred reduction (wave-private psum: no barrier) ----
    {
        const int row = tx >> 2;   // 0..15
        const int pq = tx & 3;     // px quad
        float rmax = NEG_INF;
        float cm[4];
#pragma unroll
        for (int g = 0; g < 4; ++g) {
            const int p = pq * 4 + g;
            const f32x4 v = *(const f32x4*)&psum[wv][row][p][0];
            float s = (v[0] + v[1]) + (v[2] + v[3]) + b4s;
            if (col0 + p >= WW) s = NEG_INF;
            cm[g] = s;
            rmax = fmaxf(rmax, s);
        }
        // row-max: reduce over the 4 px-quads (lanes xor 1,2)
        rmax = fmaxf(rmax, __shfl_xor(rmax, 1, 64));
        rmax = fmaxf(rmax, __shfl_xor(rmax, 2, 64));
        if (pq == 0) atomicMax(&rowbuck[rb + row], fenc(rmax));
        // col-max: reduce over the 16 rows (lanes xor 4,8,16,32)
#pragma unroll
        for (int g = 0; g < 4; ++g) {
            cm[g] = fmaxf(cm[g], __shfl_xor(cm[g], 4, 64));
            cm[g] = fmaxf(cm[g], __shfl_xor(cm[g], 8, 64));
            cm[g] = fmaxf(cm[g], __shfl_xor(cm[g], 16, 64));
            cm[g] = fmaxf(cm[g], __shfl_xor(cm[g], 32, 64));
        }
        if (row == 0) {
#pragma unroll
            for (int g = 0; g < 4; ++g) {
                const int c = col0 + pq * 4 + g;
                if (c < WW) atomicMax(&colbuck[c], fenc(cm[g]));
            }
        }
    }
}

extern "C" void kernel_launch(void* const* d_in, const int* in_sizes, int n_in,
                              void* d_out, int out_size, void* d_ws, size_t ws_size,
                              hipStream_t stream) {
    const float* in = (const float*)d_in[0];
    // d_in[1] = T_out (unused), d_in[2] = T_indices (identity, unused)
    const float* w1 = (const float*)d_in[3];
    const float* b1 = (const float*)d_in[4];
    const float* w2 = (const float*)d_in[5];
    const float* b2 = (const float*)d_in[6];
    const float* w3 = (const float*)d_in[7];
    const float* b3 = (const float*)d_in[8];
    const float* w4 = (const float*)d_in[9];
    const float* b4 = (const float*)d_in[10];

    unsigned* buck = (unsigned*)d_out;  // [0,2000) row maxes, [2000,3000) col maxes

    // fenc never produces 0, so memset-0 is a valid atomicMax identity.
    (void)hipMemsetAsync(buck, 0, 3000 * sizeof(unsigned), stream);

    dim3 block(64, 2);
    dim3 grid(32, 125);  // 32*32=1024 >= 1000 cols ; 125*16=2000 rows exactly
    mlp_max_mfma<<<grid, block, 0, stream>>>(in, w1, b1, w2, b2, w3, b3, w4, b4,
                                             buck, buck + 2000);

    decode_buckets<<<(3000 + 255) / 256, 256, 0, stream>>>(buck, 3000);
}

// Round 8
// 193.587 us; speedup vs baseline: 1.0634x; 1.0634x over previous
//
#include <hip/hip_runtime.h>

typedef _Float16 f16x8 __attribute__((ext_vector_type(8)));
typedef _Float16 f16x4 __attribute__((ext_vector_type(4)));
typedef __fp16 h16x2 __attribute__((ext_vector_type(2)));  // cvt_pkrtz native type
typedef float f32x4 __attribute__((ext_vector_type(4)));

#define HH 2000
#define WW 1000
#define HWSZ (HH * WW)
#define NEG_INF (-3.0e38f)
#define NWV 8   // waves per block (512 threads)

// ---- monotone float<->uint encoding for atomicMax on floats ----
// fenc never returns 0, so buckets are initialized with plain memset(0).
__device__ __forceinline__ unsigned fenc(float f) {
    unsigned u = __float_as_uint(f);
    return (u & 0x80000000u) ? ~u : (u | 0x80000000u);
}
__device__ __forceinline__ float fdec(unsigned k) {
    unsigned u = (k & 0x80000000u) ? (k & 0x7fffffffu) : ~k;
    return __uint_as_float(u);
}

__global__ void decode_buckets(unsigned* __restrict__ buck, int n) {
    int i = blockIdx.x * blockDim.x + threadIdx.x;
    if (i < n) {
        unsigned k = buck[i];
        ((float*)buck)[i] = fdec(k);
    }
}

// MFMA 16x16x32 f16 layouts (gfx950, verified: absmax ~2e-3):
//   A: lane holds A[m=lane&15][k=(lane>>4)*8+j]
//   B: lane holds B[k=(lane>>4)*8+j][n=lane&15]
//   D: lane holds D[row=(lane>>4)*4+reg][col=lane&15]
// A = weights (m = out-ch), B = activations (n = pixel).
// Biases folded in via constant-1 channel (K 9->10, 18->19, 36->37).
//
// R21 = R16's proven inner structure (80.4us best), repackaged into 8-wave
// (512-thread) workgroups. Session data: R13..R20 all starve at 6-9 waves/CU
// (no pipe >35%, perfect-pipeline bound ~15-20us) and neither LDS (13 blocks)
// nor VGPR (16-wave cap at VGPR=80) explains the cap -> workgroup PACKING of
// tiny 2-wave blocks is the limiter. 1000 blocks of 8 waves: VGPR cap 16
// waves/CU = exactly 2 resident blocks (LDS 49KB allows 3), steady-state
// residency ~9 -> ~16 waves/CU. Inner loop, LDS layout per wave, epilogue:
// byte-identical dataflow to R16; waves remain fully independent (no
// barriers, wave-private LDS slices).

__global__ __launch_bounds__(512) void mlp_max_mfma(
    const float* __restrict__ in,
    const float* __restrict__ w1, const float* __restrict__ b1,
    const float* __restrict__ w2, const float* __restrict__ b2,
    const float* __restrict__ w3, const float* __restrict__ b3,
    const float* __restrict__ w4, const float* __restrict__ b4,
    unsigned* __restrict__ rowbuck, unsigned* __restrict__ colbuck) {
    // per wave: 2 row-slots x (buf1[16][40] + buf2[16][40]) halves = 5120 B.
    // stride 40 halves = 80B keeps every b128 16B-aligned. Every byte read
    // is written earlier in the same iteration -> no zero-init needed.
    __shared__ _Float16 albuf[NWV][2 * 1280];
    __shared__ float rowsm[NWV][16][16];   // [wave][row-in-block][px]

    const int tx = threadIdx.x;   // 0..63
    const int wv = threadIdx.y;   // 0..7 (independent waves)
    const int px = tx & 15;
    const int q = tx >> 4;

    _Float16* s0buf1 = &albuf[wv][0];
    _Float16* s0buf2 = &albuf[wv][640];
    _Float16* s1buf1 = &albuf[wv][1280];
    _Float16* s1buf2 = &albuf[wv][1920];

    // ---- weight A-fragments (persistent, reused every iteration) ----
    f16x8 A1[2], A2[3], A3s0[3], A3s1[3];
#pragma unroll
    for (int t = 0; t < 2; ++t) {
        const int m = t * 16 + px;
#pragma unroll
        for (int j = 0; j < 8; ++j) {
            const int k = q * 8 + j;
            float v = 0.f;
            if (m < 18) {
                if (k < 9) v = w1[m * 9 + k];
                else if (k == 9) v = b1[m];
            }
            A1[t][j] = (_Float16)v;
        }
    }
#pragma unroll
    for (int t = 0; t < 3; ++t) {
        const int m = t * 16 + px;
#pragma unroll
        for (int j = 0; j < 8; ++j) {
            const int k = q * 8 + j;
            float v = 0.f;
            if (m < 36) {
                if (k < 18) v = w2[m * 18 + k];
                else if (k == 18) v = b2[m];
            }
            A2[t][j] = (_Float16)v;
        }
    }
#pragma unroll
    for (int t = 0; t < 3; ++t) {
        const int m = t * 16 + px;
#pragma unroll
        for (int j = 0; j < 8; ++j) {
            const int k = q * 8 + j;
            float v = 0.f;
            if (m < 36 && k < 32) v = w3[m * 36 + k];
            A3s0[t][j] = (_Float16)v;
            float v2 = 0.f;
            const int k2 = 32 + k;  // slice 2: ch 32..35 real, 36 = bias
            if (m < 36) {
                if (k2 < 36) v2 = w3[m * 36 + k2];
                else if (k2 == 36) v2 = b3[m];
            }
            A3s1[t][j] = (_Float16)v2;
        }
    }

    float w4r[3][4];
#pragma unroll
    for (int t = 0; t < 3; ++t)
#pragma unroll
        for (int rg = 0; rg < 4; ++rg) {
            const int ch = t * 16 + q * 4 + rg;
            w4r[t][rg] = (ch < 36) ? w4[ch] : 0.f;
        }
    const float b4s = b4[0];

    const int col = blockIdx.x * (NWV * 16) + wv * 16 + px;
    const int colc = (col < WW) ? col : (WW - 1);
    const bool colok = (col < WW);
    const int rb = blockIdx.y * 16;

    float colmax = NEG_INF;
    const f32x4 zf4 = {0.f, 0.f, 0.f, 0.f};
    const h16x2 z2 = {(__fp16)0.f, (__fp16)0.f};

    union U8 { f16x8 v; h16x2 h[4]; };
    union U4 { f16x4 v; h16x2 h[2]; };

    // ---- precomputed per-lane 32-bit element offsets (loop-invariant) ----
    int off[8];
#pragma unroll
    for (int j = 0; j < 8; ++j) {
        const int c = q * 8 + j;
        off[j] = (c < 9) ? (c * HWSZ + colc) : 0;
    }

    // ---- double-buffered raw input regs: [j] for rows (r, r+1) ----
    float ca[8], cb[8], na[8], nb[8];

    auto LOAD = [&](int r, float (&v0)[8], float (&v1)[8]) {
        const float* rbase = in + (size_t)r * WW;   // wave-uniform -> SGPR base
#pragma unroll
        for (int j = 0; j < 8; ++j) {
            const int c = q * 8 + j;
            float x0 = (c == 9) ? 1.f : 0.f;  // bias ch / zero pad
            float x1 = x0;
            if (c < 9) {
                x0 = rbase[off[j]];
                x1 = rbase[off[j] + WW];   // folds into inst offset:4000
            }
            v0[j] = x0;
            v1[j] = x1;
        }
    };

    auto COMPUTE = [&](int it, const float (&v0)[8], const float (&v1)[8]) {
        // ---- pack inputs to f16 (packed RTZ cvt) ----
        U8 b0u, b1u;
#pragma unroll
        for (int j = 0; j < 4; ++j) {
            b0u.h[j] = __builtin_amdgcn_cvt_pkrtz(v0[2 * j], v0[2 * j + 1]);
            b1u.h[j] = __builtin_amdgcn_cvt_pkrtz(v1[2 * j], v1[2 * j + 1]);
        }
        const f16x8 bin0 = b0u.v;
        const f16x8 bin1 = b1u.v;

        // ---- layer 1 (bias via k=9) ----
        f32x4 D1a[2], D1b[2];
#pragma unroll
        for (int t = 0; t < 2; ++t) {
            D1a[t] = __builtin_amdgcn_mfma_f32_16x16x32_f16(A1[t], bin0, zf4, 0, 0, 0);
            D1b[t] = __builtin_amdgcn_mfma_f32_16x16x32_f16(A1[t], bin1, zf4, 0, 0, 0);
        }
#pragma unroll
        for (int t = 0; t < 2; ++t) {
            U4 h0, h1;
            h0.h[0] = __builtin_elementwise_max(
                __builtin_amdgcn_cvt_pkrtz(D1a[t][0], D1a[t][1]), z2);
            h0.h[1] = __builtin_elementwise_max(
                __builtin_amdgcn_cvt_pkrtz(D1a[t][2], D1a[t][3]), z2);
            h1.h[0] = __builtin_elementwise_max(
                __builtin_amdgcn_cvt_pkrtz(D1b[t][0], D1b[t][1]), z2);
            h1.h[1] = __builtin_elementwise_max(
                __builtin_amdgcn_cvt_pkrtz(D1b[t][2], D1b[t][3]), z2);
            if (t == 1 && q == 0) {  // ch18 = constant-1 bias channel for L2
                h0.v[2] = (_Float16)1.f;
                h1.v[2] = (_Float16)1.f;
            }
            *(f16x4*)&s0buf1[px * 40 + t * 16 + q * 4] = h0.v;
            *(f16x4*)&s1buf1[px * 40 + t * 16 + q * 4] = h1.v;
        }
        const f16x8 B2a = *(const f16x8*)&s0buf1[px * 40 + q * 8];
        const f16x8 B2b = *(const f16x8*)&s1buf1[px * 40 + q * 8];

        // ---- layer 2 (bias via k=18) ----
        f32x4 D2a[3], D2b[3];
#pragma unroll
        for (int t = 0; t < 3; ++t) {
            D2a[t] = __builtin_amdgcn_mfma_f32_16x16x32_f16(A2[t], B2a, zf4, 0, 0, 0);
            D2b[t] = __builtin_amdgcn_mfma_f32_16x16x32_f16(A2[t], B2b, zf4, 0, 0, 0);
        }
#pragma unroll
        for (int t = 0; t < 3; ++t) {
            U4 h0, h1;
            h0.h[0] = __builtin_elementwise_max(
                __builtin_amdgcn_cvt_pkrtz(D2a[t][0], D2a[t][1]), z2);
            h0.h[1] = __builtin_elementwise_max(
                __builtin_amdgcn_cvt_pkrtz(D2a[t][2], D2a[t][3]), z2);
            h1.h[0] = __builtin_elementwise_max(
                __builtin_amdgcn_cvt_pkrtz(D2b[t][0], D2b[t][1]), z2);
            h1.h[1] = __builtin_elementwise_max(
                __builtin_amdgcn_cvt_pkrtz(D2b[t][2], D2b[t][3]), z2);
            if (t < 2) {
                *(f16x4*)&s0buf2[px * 40 + t * 16 + q * 4] = h0.v;
                *(f16x4*)&s1buf2[px * 40 + t * 16 + q * 4] = h1.v;
            } else if (q == 0) {  // ch 32..35 only
                *(f16x4*)&s0buf2[px * 40 + 32] = h0.v;
                *(f16x4*)&s1buf2[px * 40 + 32] = h1.v;
            }
        }
        const f16x8 B3a0 = *(const f16x8*)&s0buf2[px * 40 + q * 8];
        const f16x8 B3b0 = *(const f16x8*)&s1buf2[px * 40 + q * 8];
        f16x8 B3a1 = {0, 0, 0, 0, 0, 0, 0, 0};
        f16x8 B3b1 = {0, 0, 0, 0, 0, 0, 0, 0};
        if (q == 0) {  // slice2: j0..3 = ch32..35, j4 = bias (=1)
            const f16x4 t0 = *(const f16x4*)&s0buf2[px * 40 + 32];
            const f16x4 t1 = *(const f16x4*)&s1buf2[px * 40 + 32];
#pragma unroll
            for (int j = 0; j < 4; ++j) { B3a1[j] = t0[j]; B3b1[j] = t1[j]; }
            B3a1[4] = (_Float16)1.f;
            B3b1[4] = (_Float16)1.f;
        }

        // ---- layer 3 (two K-slices, bias via k=36) ----
        f32x4 D3a[3], D3b[3];
#pragma unroll
        for (int t = 0; t < 3; ++t) {
            D3a[t] = __builtin_amdgcn_mfma_f32_16x16x32_f16(A3s0[t], B3a0, zf4, 0, 0, 0);
            D3a[t] = __builtin_amdgcn_mfma_f32_16x16x32_f16(A3s1[t], B3a1, D3a[t], 0, 0, 0);
            D3b[t] = __builtin_amdgcn_mfma_f32_16x16x32_f16(A3s0[t], B3b0, zf4, 0, 0, 0);
            D3b[t] = __builtin_amdgcn_mfma_f32_16x16x32_f16(A3s1[t], B3b1, D3b[t], 0, 0, 0);
        }

        // ---- layer 4: parallel 4-acc dot + 2 sum-shuffles ----
        float sa0 = 0.f, sa1 = 0.f, sa2 = 0.f, sa3 = 0.f;
        float sb0 = 0.f, sb1 = 0.f, sb2 = 0.f, sb3 = 0.f;
#pragma unroll
        for (int t = 0; t < 3; ++t) {
            sa0 = fmaf(w4r[t][0], fmaxf(D3a[t][0], 0.f), sa0);
            sa1 = fmaf(w4r[t][1], fmaxf(D3a[t][1], 0.f), sa1);
            sa2 = fmaf(w4r[t][2], fmaxf(D3a[t][2], 0.f), sa2);
            sa3 = fmaf(w4r[t][3], fmaxf(D3a[t][3], 0.f), sa3);
            sb0 = fmaf(w4r[t][0], fmaxf(D3b[t][0], 0.f), sb0);
            sb1 = fmaf(w4r[t][1], fmaxf(D3b[t][1], 0.f), sb1);
            sb2 = fmaf(w4r[t][2], fmaxf(D3b[t][2], 0.f), sb2);
            sb3 = fmaf(w4r[t][3], fmaxf(D3b[t][3], 0.f), sb3);
        }
        float sa = (sa0 + sa1) + (sa2 + sa3);
        float sb = (sb0 + sb1) + (sb2 + sb3);
        sa += __shfl_xor(sa, 16, 64); sb += __shfl_xor(sb, 16, 64);
        sa += __shfl_xor(sa, 32, 64); sb += __shfl_xor(sb, 32, 64);
        sa += b4s; sb += b4s;

        sa = colok ? sa : NEG_INF;
        sb = colok ? sb : NEG_INF;
        colmax = fmaxf(colmax, fmaxf(sa, sb));

        // every lane holds the full s(px); scatter to [row][px], fire-and-forget.
        // banks: row even->0..15, row odd->16..31 -> 32 active lanes, 0 conflicts.
        if (q == 0) rowsm[wv][it * 2][px] = sa;
        else if (q == 1) rowsm[wv][it * 2 + 1][px] = sb;
    };

    // ---- main loop: 8 iterations (16 rows), depth-1 ping-pong prefetch ----
    LOAD(rb, ca, cb);
#pragma unroll 1
    for (int it = 0; it < 8; it += 2) {
        LOAD(rb + (it + 1) * 2, na, nb);   // prefetch odd half-step
        COMPUTE(it, ca, cb);
        if (it < 6) LOAD(rb + (it + 2) * 2, ca, cb);  // prefetch next even
        COMPUTE(it + 1, na, nb);
    }

    // ---- end-of-wave flush (no barrier: rowsm slice is wave-private) ----
    if (q == 0 && colok) atomicMax(&colbuck[col], fenc(colmax));
    if (tx < 16) {
        const f32x4 v0 = *(const f32x4*)&rowsm[wv][tx][0];
        const f32x4 v1 = *(const f32x4*)&rowsm[wv][tx][4];
        const f32x4 v2 = *(const f32x4*)&rowsm[wv][tx][8];
        const f32x4 v3 = *(const f32x4*)&rowsm[wv][tx][12];
        float m = NEG_INF;
#pragma unroll
        for (int j = 0; j < 4; ++j) {
            m = fmaxf(m, fmaxf(fmaxf(v0[j], v1[j]), fmaxf(v2[j], v3[j])));
        }
        atomicMax(&rowbuck[rb + tx], fenc(m));
    }
}

extern "C" void kernel_launch(void* const* d_in, const int* in_sizes, int n_in,
                              void* d_out, int out_size, void* d_ws, size_t ws_size,
                              hipStream_t stream) {
    const float* in = (const float*)d_in[0];
    // d_in[1] = T_out (unused), d_in[2] = T_indices (identity, unused)
    const float* w1 = (const float*)d_in[3];
    const float* b1 = (const float*)d_in[4];
    const float* w2 = (const float*)d_in[5];
    const float* b2 = (const float*)d_in[6];
    const float* w3 = (const float*)d_in[7];
    const float* b3 = (const float*)d_in[8];
    const float* w4 = (const float*)d_in[9];
    const float* b4 = (const float*)d_in[10];

    unsigned* buck = (unsigned*)d_out;  // [0,2000) row maxes, [2000,3000) col maxes

    // fenc never produces 0, so memset-0 is a valid atomicMax identity.
    (void)hipMemsetAsync(buck, 0, 3000 * sizeof(unsigned), stream);

    dim3 block(64, NWV);   // 512 threads = 8 independent waves
    dim3 grid(8, 125);     // 8*128=1024 >= 1000 cols ; 125*16=2000 rows exactly
    mlp_max_mfma<<<grid, block, 0, stream>>>(in, w1, b1, w2, b2, w3, b3, w4, b4,
                                             buck, buck + 2000);

    decode_buckets<<<(3000 + 255) / 256, 256, 0, stream>>>(buck, 3000);
}

// Round 9
// 182.534 us; speedup vs baseline: 1.1278x; 1.0606x over previous
//
#include <hip/hip_runtime.h>

typedef _Float16 f16x8 __attribute__((ext_vector_type(8)));
typedef _Float16 f16x4 __attribute__((ext_vector_type(4)));
typedef __fp16 h16x2 __attribute__((ext_vector_type(2)));  // cvt_pkrtz native type
typedef float f32x4 __attribute__((ext_vector_type(4)));

#define HH 2000
#define WW 1000
#define HWSZ (HH * WW)
#define NEG_INF (-3.0e38f)

// ---- monotone float<->uint encoding for atomicMax on floats ----
// fenc never returns 0, so buckets are initialized with plain memset(0).
__device__ __forceinline__ unsigned fenc(float f) {
    unsigned u = __float_as_uint(f);
    return (u & 0x80000000u) ? ~u : (u | 0x80000000u);
}
__device__ __forceinline__ float fdec(unsigned k) {
    unsigned u = (k & 0x80000000u) ? (k & 0x7fffffffu) : ~k;
    return __uint_as_float(u);
}

__global__ void decode_buckets(unsigned* __restrict__ buck, int n) {
    int i = blockIdx.x * blockDim.x + threadIdx.x;
    if (i < n) {
        unsigned k = buck[i];
        ((float*)buck)[i] = fdec(k);
    }
}

// MFMA 16x16x32 f16 layouts (gfx950, verified: absmax ~2e-3):
//   A: lane holds A[m=lane&15][k=(lane>>4)*8+j]
//   B: lane holds B[k=(lane>>4)*8+j][n=lane&15]
//   D: lane holds D[row=(lane>>4)*4+reg][col=lane&15]
// A = weights (m = out-ch), B = activations (n = pixel).
//
// R22: instruction-diet round. Evidence: R13->R16 (-30% instr -> -27% time)
// is the ONLY change that ever moved duration; all occupancy/latency levers
// (R17-R21) were neutral. Cuts, on the proven R16 structure:
// (a) layer-1 k-permutation: k=(q,j): j0->ch q, j1->ch 4+q, j2->(q0:ch8,
//     q1:bias). A and B just have to agree on the k<->ch map. Loads: 16
//     quarter-occupancy instrs -> 6 full-occupancy; packs 8->4; input
//     buffers 32->12 VGPRs.
// (b) L3 slice-1 via pre-initialized LDS slots (1.0@36, 0@37-39, written
//     once): in-loop q==0 gather/insert dance -> one unmasked ds_read_b128.
// (c) L4 dot via v_dot2_f32_f16: relu+cvt_pkrtz pairs + 6 fdot2/row
//     replaces 12 fma + 12 max per row; w4 pre-packed h16x2.

__global__ __launch_bounds__(128) void mlp_max_mfma(
    const float* __restrict__ in,
    const float* __restrict__ w1, const float* __restrict__ b1,
    const float* __restrict__ w2, const float* __restrict__ b2,
    const float* __restrict__ w3, const float* __restrict__ b3,
    const float* __restrict__ w4, const float* __restrict__ b4,
    unsigned* __restrict__ rowbuck, unsigned* __restrict__ colbuck) {
    // per wave: 2 row-slots x (buf1[16][40] + buf2[16][40]) halves = 5120 B.
    // stride 40 halves = 80B keeps every b128 16B-aligned.
    __shared__ _Float16 albuf[2][2 * 1280];
    __shared__ float rowsm[2][16][16];   // [wave][row-in-block][px]

    const int tx = threadIdx.x;   // 0..63
    const int wv = threadIdx.y;   // 0..1 (independent waves)
    const int px = tx & 15;
    const int q = tx >> 4;

    _Float16* s0buf1 = &albuf[wv][0];
    _Float16* s0buf2 = &albuf[wv][640];
    _Float16* s1buf1 = &albuf[wv][1280];
    _Float16* s1buf2 = &albuf[wv][1920];

    // ---- L3 slice-1 constant slots: 1.0 @ k=36 (bias), 0 @ 37..39.
    // t<2 epilogue writes cover 0-31, t2 covers 32-35 -> slots 36-39 are
    // written exactly once here (wave-private LDS, in-wave DS ordering).
    if (q == 0) {
        const f16x4 binit = {(_Float16)1.f, (_Float16)0.f, (_Float16)0.f, (_Float16)0.f};
        *(f16x4*)&s0buf2[px * 40 + 36] = binit;
        *(f16x4*)&s1buf2[px * 40 + 36] = binit;
    }

    // ---- weight A-fragments (persistent, reused every iteration) ----
    // Layer-1 k-map: j0 -> ch q ; j1 -> ch 4+q ; j2 -> (q0: ch8, q1: bias).
    f16x8 A1[2], A2[3], A3s0[3], A3s1[3];
#pragma unroll
    for (int t = 0; t < 2; ++t) {
        const int m = t * 16 + px;
#pragma unroll
        for (int j = 0; j < 8; ++j) {
            float v = 0.f;
            if (m < 18) {
                if (j == 0) v = w1[m * 9 + q];
                else if (j == 1) v = w1[m * 9 + 4 + q];
                else if (j == 2) {
                    if (q == 0) v = w1[m * 9 + 8];
                    else if (q == 1) v = b1[m];
                }
            }
            A1[t][j] = (_Float16)v;
        }
    }
#pragma unroll
    for (int t = 0; t < 3; ++t) {
        const int m = t * 16 + px;
#pragma unroll
        for (int j = 0; j < 8; ++j) {
            const int k = q * 8 + j;
            float v = 0.f;
            if (m < 36) {
                if (k < 18) v = w2[m * 18 + k];
                else if (k == 18) v = b2[m];
            }
            A2[t][j] = (_Float16)v;
        }
    }
#pragma unroll
    for (int t = 0; t < 3; ++t) {
        const int m = t * 16 + px;
#pragma unroll
        for (int j = 0; j < 8; ++j) {
            const int k = q * 8 + j;
            float v = 0.f;
            if (m < 36 && k < 32) v = w3[m * 36 + k];
            A3s0[t][j] = (_Float16)v;
            float v2 = 0.f;
            const int k2 = 32 + k;  // slice 2: ch 32..35 real, 36 = bias
            if (m < 36) {
                if (k2 < 36) v2 = w3[m * 36 + k2];
                else if (k2 == 36) v2 = b3[m];
            }
            A3s1[t][j] = (_Float16)v2;
        }
    }

    // w4 packed as h16x2 pairs for v_dot2_f32_f16
    h16x2 w4p[3][2];
#pragma unroll
    for (int t = 0; t < 3; ++t)
#pragma unroll
        for (int i = 0; i < 2; ++i) {
            const int c0 = t * 16 + q * 4 + 2 * i;
            const int c1 = c0 + 1;
            w4p[t][i] = __builtin_amdgcn_cvt_pkrtz(c0 < 36 ? w4[c0] : 0.f,
                                                   c1 < 36 ? w4[c1] : 0.f);
        }
    const float b4s = b4[0];

    const int col = blockIdx.x * 32 + wv * 16 + px;
    const int colc = (col < WW) ? col : (WW - 1);
    const bool colok = (col < WW);
    const int rb = blockIdx.y * 16;

    float colmax = NEG_INF;
    const f32x4 zf4 = {0.f, 0.f, 0.f, 0.f};
    const h16x2 z2 = {(__fp16)0.f, (__fp16)0.f};

    union U8 { f16x8 v; h16x2 h[4]; };
    union U4 { f16x4 v; h16x2 h[2]; };

    // ---- per-lane 32-bit element offsets for the k-permuted loads ----
    const int off0 = q * HWSZ + colc;        // ch q        (j=0)
    const int off1 = (4 + q) * HWSZ + colc;  // ch 4+q      (j=1)
    const int off2 = 8 * HWSZ + colc;        // ch 8 (q==0) (j=2)
    const float j2fill = (q == 1) ? 1.f : 0.f;  // bias / zero for j=2, q>=1

    // ---- double-buffered raw input regs: [j] for rows (r, r+1) ----
    float ca[3], cb[3], na[3], nb[3];

    auto LOAD = [&](int r, float (&v0)[3], float (&v1)[3]) {
        const float* rbase = in + (size_t)r * WW;   // wave-uniform base
        v0[0] = rbase[off0]; v1[0] = rbase[off0 + WW];
        v0[1] = rbase[off1]; v1[1] = rbase[off1 + WW];
        float x0 = j2fill, x1 = j2fill;
        if (q == 0) { x0 = rbase[off2]; x1 = rbase[off2 + WW]; }
        v0[2] = x0; v1[2] = x1;
    };

    auto COMPUTE = [&](int it, const float (&v0)[3], const float (&v1)[3]) {
        // ---- pack inputs to f16 (k-permuted layout; e4..e7 = 0) ----
        U8 b0u, b1u;
        b0u.h[0] = __builtin_amdgcn_cvt_pkrtz(v0[0], v0[1]);
        b0u.h[1] = __builtin_amdgcn_cvt_pkrtz(v0[2], 0.f);
        b0u.h[2] = z2; b0u.h[3] = z2;
        b1u.h[0] = __builtin_amdgcn_cvt_pkrtz(v1[0], v1[1]);
        b1u.h[1] = __builtin_amdgcn_cvt_pkrtz(v1[2], 0.f);
        b1u.h[2] = z2; b1u.h[3] = z2;
        const f16x8 bin0 = b0u.v;
        const f16x8 bin1 = b1u.v;

        // ---- layer 1 (bias folded into k-map) ----
        f32x4 D1a[2], D1b[2];
#pragma unroll
        for (int t = 0; t < 2; ++t) {
            D1a[t] = __builtin_amdgcn_mfma_f32_16x16x32_f16(A1[t], bin0, zf4, 0, 0, 0);
            D1b[t] = __builtin_amdgcn_mfma_f32_16x16x32_f16(A1[t], bin1, zf4, 0, 0, 0);
        }
#pragma unroll
        for (int t = 0; t < 2; ++t) {
            U4 h0, h1;
            h0.h[0] = __builtin_elementwise_max(
                __builtin_amdgcn_cvt_pkrtz(D1a[t][0], D1a[t][1]), z2);
            h0.h[1] = __builtin_elementwise_max(
                __builtin_amdgcn_cvt_pkrtz(D1a[t][2], D1a[t][3]), z2);
            h1.h[0] = __builtin_elementwise_max(
                __builtin_amdgcn_cvt_pkrtz(D1b[t][0], D1b[t][1]), z2);
            h1.h[1] = __builtin_elementwise_max(
                __builtin_amdgcn_cvt_pkrtz(D1b[t][2], D1b[t][3]), z2);
            if (t == 1 && q == 0) {  // ch18 = constant-1 bias channel for L2
                h0.v[2] = (_Float16)1.f;
                h1.v[2] = (_Float16)1.f;
            }
            *(f16x4*)&s0buf1[px * 40 + t * 16 + q * 4] = h0.v;
            *(f16x4*)&s1buf1[px * 40 + t * 16 + q * 4] = h1.v;
        }
        const f16x8 B2a = *(const f16x8*)&s0buf1[px * 40 + q * 8];
        const f16x8 B2b = *(const f16x8*)&s1buf1[px * 40 + q * 8];

        // ---- layer 2 (bias via k=18) ----
        f32x4 D2a[3], D2b[3];
#pragma unroll
        for (int t = 0; t < 3; ++t) {
            D2a[t] = __builtin_amdgcn_mfma_f32_16x16x32_f16(A2[t], B2a, zf4, 0, 0, 0);
            D2b[t] = __builtin_amdgcn_mfma_f32_16x16x32_f16(A2[t], B2b, zf4, 0, 0, 0);
        }
#pragma unroll
        for (int t = 0; t < 3; ++t) {
            U4 h0, h1;
            h0.h[0] = __builtin_elementwise_max(
                __builtin_amdgcn_cvt_pkrtz(D2a[t][0], D2a[t][1]), z2);
            h0.h[1] = __builtin_elementwise_max(
                __builtin_amdgcn_cvt_pkrtz(D2a[t][2], D2a[t][3]), z2);
            h1.h[0] = __builtin_elementwise_max(
                __builtin_amdgcn_cvt_pkrtz(D2b[t][0], D2b[t][1]), z2);
            h1.h[1] = __builtin_elementwise_max(
                __builtin_amdgcn_cvt_pkrtz(D2b[t][2], D2b[t][3]), z2);
            if (t < 2) {
                *(f16x4*)&s0buf2[px * 40 + t * 16 + q * 4] = h0.v;
                *(f16x4*)&s1buf2[px * 40 + t * 16 + q * 4] = h1.v;
            } else if (q == 0) {  // ch 32..35 only (36-39 are the constants)
                *(f16x4*)&s0buf2[px * 40 + 32] = h0.v;
                *(f16x4*)&s1buf2[px * 40 + 32] = h1.v;
            }
        }
        const f16x8 B3a0 = *(const f16x8*)&s0buf2[px * 40 + q * 8];
        const f16x8 B3b0 = *(const f16x8*)&s1buf2[px * 40 + q * 8];
        // slice-1 frag: chs 32-35 + 1.0@36 + 0@37-39 (pre-initialized).
        // Only q==0 lanes carry nonzero A3s1 weights; other lanes' reads
        // broadcast the same finite data (harmless).
        const f16x8 B3a1 = *(const f16x8*)&s0buf2[px * 40 + 32];
        const f16x8 B3b1 = *(const f16x8*)&s1buf2[px * 40 + 32];

        // ---- layer 3 (two K-slices, bias via k=36) ----
        f32x4 D3a[3], D3b[3];
#pragma unroll
        for (int t = 0; t < 3; ++t) {
            D3a[t] = __builtin_amdgcn_mfma_f32_16x16x32_f16(A3s0[t], B3a0, zf4, 0, 0, 0);
            D3a[t] = __builtin_amdgcn_mfma_f32_16x16x32_f16(A3s1[t], B3a1, D3a[t], 0, 0, 0);
            D3b[t] = __builtin_amdgcn_mfma_f32_16x16x32_f16(A3s0[t], B3b0, zf4, 0, 0, 0);
            D3b[t] = __builtin_amdgcn_mfma_f32_16x16x32_f16(A3s1[t], B3b1, D3b[t], 0, 0, 0);
        }

        // ---- layer 4: packed relu + v_dot2_f32_f16, then 2 sum-shuffles ----
        float sa0 = 0.f, sa1 = 0.f, sb0 = 0.f, sb1 = 0.f;
#pragma unroll
        for (int t = 0; t < 3; ++t) {
            const h16x2 pa0 = __builtin_elementwise_max(
                __builtin_amdgcn_cvt_pkrtz(D3a[t][0], D3a[t][1]), z2);
            const h16x2 pa1 = __builtin_elementwise_max(
                __builtin_amdgcn_cvt_pkrtz(D3a[t][2], D3a[t][3]), z2);
            const h16x2 pb0 = __builtin_elementwise_max(
                __builtin_amdgcn_cvt_pkrtz(D3b[t][0], D3b[t][1]), z2);
            const h16x2 pb1 = __builtin_elementwise_max(
                __builtin_amdgcn_cvt_pkrtz(D3b[t][2], D3b[t][3]), z2);
            sa0 = __builtin_amdgcn_fdot2(pa0, w4p[t][0], sa0, false);
            sa1 = __builtin_amdgcn_fdot2(pa1, w4p[t][1], sa1, false);
            sb0 = __builtin_amdgcn_fdot2(pb0, w4p[t][0], sb0, false);
            sb1 = __builtin_amdgcn_fdot2(pb1, w4p[t][1], sb1, false);
        }
        float sa = sa0 + sa1;
        float sb = sb0 + sb1;
        sa += __shfl_xor(sa, 16, 64); sb += __shfl_xor(sb, 16, 64);
        sa += __shfl_xor(sa, 32, 64); sb += __shfl_xor(sb, 32, 64);
        sa += b4s; sb += b4s;

        sa = colok ? sa : NEG_INF;
        sb = colok ? sb : NEG_INF;
        colmax = fmaxf(colmax, fmaxf(sa, sb));

        // every lane holds the full s(px); scatter to [row][px].
        if (q == 0) rowsm[wv][it * 2][px] = sa;
        else if (q == 1) rowsm[wv][it * 2 + 1][px] = sb;
    };

    // ---- main loop: 8 iterations (16 rows), depth-1 ping-pong prefetch ----
    LOAD(rb, ca, cb);
#pragma unroll 1
    for (int it = 0; it < 8; it += 2) {
        LOAD(rb + (it + 1) * 2, na, nb);   // prefetch odd half-step
        COMPUTE(it, ca, cb);
        if (it < 6) LOAD(rb + (it + 2) * 2, ca, cb);  // prefetch next even
        COMPUTE(it + 1, na, nb);
    }

    // ---- end-of-wave flush (no barrier: rowsm slice is wave-private) ----
    if (q == 0 && colok) atomicMax(&colbuck[col], fenc(colmax));
    if (tx < 16) {
        const f32x4 v0 = *(const f32x4*)&rowsm[wv][tx][0];
        const f32x4 v1 = *(const f32x4*)&rowsm[wv][tx][4];
        const f32x4 v2 = *(const f32x4*)&rowsm[wv][tx][8];
        const f32x4 v3 = *(const f32x4*)&rowsm[wv][tx][12];
        float m = NEG_INF;
#pragma unroll
        for (int j = 0; j < 4; ++j) {
            m = fmaxf(m, fmaxf(fmaxf(v0[j], v1[j]), fmaxf(v2[j], v3[j])));
        }
        atomicMax(&rowbuck[rb + tx], fenc(m));
    }
}

extern "C" void kernel_launch(void* const* d_in, const int* in_sizes, int n_in,
                              void* d_out, int out_size, void* d_ws, size_t ws_size,
                              hipStream_t stream) {
    const float* in = (const float*)d_in[0];
    // d_in[1] = T_out (unused), d_in[2] = T_indices (identity, unused)
    const float* w1 = (const float*)d_in[3];
    const float* b1 = (const float*)d_in[4];
    const float* w2 = (const float*)d_in[5];
    const float* b2 = (const float*)d_in[6];
    const float* w3 = (const float*)d_in[7];
    const float* b3 = (const float*)d_in[8];
    const float* w4 = (const float*)d_in[9];
    const float* b4 = (const float*)d_in[10];

    unsigned* buck = (unsigned*)d_out;  // [0,2000) row maxes, [2000,3000) col maxes

    // fenc never produces 0, so memset-0 is a valid atomicMax identity.
    (void)hipMemsetAsync(buck, 0, 3000 * sizeof(unsigned), stream);

    dim3 block(64, 2);
    dim3 grid(32, 125);  // 32*32=1024 >= 1000 cols ; 125*16=2000 rows exactly
    mlp_max_mfma<<<grid, block, 0, stream>>>(in, w1, b1, w2, b2, w3, b3, w4, b4,
                                             buck, buck + 2000);

    decode_buckets<<<(3000 + 255) / 256, 256, 0, stream>>>(buck, 3000);
}

// Round 10
// 175.087 us; speedup vs baseline: 1.1758x; 1.0425x over previous
//
#include <hip/hip_runtime.h>

typedef _Float16 f16x8 __attribute__((ext_vector_type(8)));
typedef _Float16 f16x4 __attribute__((ext_vector_type(4)));
typedef __fp16 h16x2 __attribute__((ext_vector_type(2)));  // cvt_pkrtz native type
typedef float f32x4 __attribute__((ext_vector_type(4)));

#define HH 2000
#define WW 1000
#define HWSZ (HH * WW)
#define NEG_INF (-3.0e38f)

// ---- monotone float<->uint encoding for atomicMax on floats ----
// fenc never returns 0, so buckets are initialized with plain memset(0).
__device__ __forceinline__ unsigned fenc(float f) {
    unsigned u = __float_as_uint(f);
    return (u & 0x80000000u) ? ~u : (u | 0x80000000u);
}
__device__ __forceinline__ float fdec(unsigned k) {
    unsigned u = (k & 0x80000000u) ? (k & 0x7fffffffu) : ~k;
    return __uint_as_float(u);
}

__global__ void decode_buckets(unsigned* __restrict__ buck, int n) {
    int i = blockIdx.x * blockDim.x + threadIdx.x;
    if (i < n) {
        unsigned k = buck[i];
        ((float*)buck)[i] = fdec(k);
    }
}

// MFMA 16x16x32 f16 layouts (gfx950, verified: absmax ~2e-3):
//   A: lane holds A[m=lane&15][k=(lane>>4)*8+j]
//   B: lane holds B[k=(lane>>4)*8+j][n=lane&15]
//   D: lane holds D[row=(lane>>4)*4+reg][col=lane&15]
//
// R23: ZERO-LDS layer transitions. Session invariant: one iteration completes
// per CU every ~810cy regardless of waves/VALU/loads (R16-R22); the constant
// across all variants is ~22 DS ops/iter (LDS write->read per layer + their
// waitcnt chains). Fix: redefine each layer's A-fragment k<->channel map so
// the NEXT layer's B operand IS the current layer's packed epilogue regs:
//   D gives lane(g,px) chs 4g+reg; pack pairs -> P0=(4g,4g+1), P1=(4g+2,4g+3).
//   A2 k-map: k=8g+j <-> ch 4g+j (j<4); g0 j4,5 -> ch16,17; g0 j6 -> bias.
//     => B2 = {P0, P1, Q0, cB2}   (zero moves; K used 19/32)
//   A3s0 k-map: k=8g+j <-> ch 4g+j (j<4), ch 16+4g+(j-4) (j>=4)
//     => B3s0 = {T0a, T0b, T1a, T1b}
//   A3s1: g0 j0-3 -> ch32-35, g0 j4 -> bias => B3s1 = {T2a, T2b, cB3, 0}.
// Garbage/zero channels annihilated by zero rows of A (R22-verified trick).
// Remaining DS per iter: 4 bpermute (L4 sum) + 2 rowsm writes. LDS 12KB->2KB.

__global__ __launch_bounds__(128) void mlp_max_mfma(
    const float* __restrict__ in,
    const float* __restrict__ w1, const float* __restrict__ b1,
    const float* __restrict__ w2, const float* __restrict__ b2,
    const float* __restrict__ w3, const float* __restrict__ b3,
    const float* __restrict__ w4, const float* __restrict__ b4,
    unsigned* __restrict__ rowbuck, unsigned* __restrict__ colbuck) {
    __shared__ float rowsm[2][16][16];   // [wave][row-in-block][px]

    const int tx = threadIdx.x;   // 0..63
    const int wv = threadIdx.y;   // 0..1 (independent waves)
    const int px = tx & 15;
    const int q = tx >> 4;        // lane group g

    // ---- weight A-fragments (persistent; k-maps documented above) ----
    f16x8 A1[2], A2[3], A3s0[3], A3s1[3];
    // L1 (R22-verified k-map): j0 -> ch q ; j1 -> ch 4+q ; j2 -> (q0: ch8,
    // q1: bias); j>=3 zero.
#pragma unroll
    for (int t = 0; t < 2; ++t) {
        const int m = t * 16 + px;
#pragma unroll
        for (int j = 0; j < 8; ++j) {
            float v = 0.f;
            if (m < 18) {
                if (j == 0) v = w1[m * 9 + q];
                else if (j == 1) v = w1[m * 9 + 4 + q];
                else if (j == 2) {
                    if (q == 0) v = w1[m * 9 + 8];
                    else if (q == 1) v = b1[m];
                }
            }
            A1[t][j] = (_Float16)v;
        }
    }
    // L2: k=8q+j <-> ch 4q+j (j<4); q0: j4->ch16, j5->ch17, j6->bias.
#pragma unroll
    for (int t = 0; t < 3; ++t) {
        const int m = t * 16 + px;
#pragma unroll
        for (int j = 0; j < 8; ++j) {
            float v = 0.f;
            if (m < 36) {
                if (j < 4) v = w2[m * 18 + 4 * q + j];
                else if (q == 0) {
                    if (j == 4) v = w2[m * 18 + 16];
                    else if (j == 5) v = w2[m * 18 + 17];
                    else if (j == 6) v = b2[m];
                }
            }
            A2[t][j] = (_Float16)v;
        }
    }
    // L3 slice0: k=8q+j <-> ch 4q+j (j<4), ch 16+4q+(j-4) (j>=4).
    // L3 slice1: q0 j0-3 -> ch 32..35 ; q0 j4 -> bias ; else 0.
#pragma unroll
    for (int t = 0; t < 3; ++t) {
        const int m = t * 16 + px;
#pragma unroll
        for (int j = 0; j < 8; ++j) {
            float v = 0.f;
            if (m < 36) {
                const int ch = (j < 4) ? (4 * q + j) : (16 + 4 * q + (j - 4));
                v = w3[m * 36 + ch];
            }
            A3s0[t][j] = (_Float16)v;
            float v2 = 0.f;
            if (m < 36 && q == 0) {
                if (j < 4) v2 = w3[m * 36 + 32 + j];
                else if (j == 4) v2 = b3[m];
            }
            A3s1[t][j] = (_Float16)v2;
        }
    }

    // w4 packed as h16x2 pairs for v_dot2_f32_f16 (per-lane chs 16t+4q+rg)
    h16x2 w4p[3][2];
#pragma unroll
    for (int t = 0; t < 3; ++t)
#pragma unroll
        for (int i = 0; i < 2; ++i) {
            const int c0 = t * 16 + q * 4 + 2 * i;
            const int c1 = c0 + 1;
            w4p[t][i] = __builtin_amdgcn_cvt_pkrtz(c0 < 36 ? w4[c0] : 0.f,
                                                   c1 < 36 ? w4[c1] : 0.f);
        }
    const float b4s = b4[0];

    const int col = blockIdx.x * 32 + wv * 16 + px;
    const int colc = (col < WW) ? col : (WW - 1);
    const bool colok = (col < WW);
    const int rb = blockIdx.y * 16;

    float colmax = NEG_INF;
    const f32x4 zf4 = {0.f, 0.f, 0.f, 0.f};
    const h16x2 z2 = {(__fp16)0.f, (__fp16)0.f};
    // loop-invariant bias-channel constants (g0 carries (1.0, 0))
    const h16x2 cB = (q == 0) ? __builtin_amdgcn_cvt_pkrtz(1.f, 0.f) : z2;

    union U8 { f16x8 v; h16x2 h[4]; };

    // ---- per-lane 32-bit element offsets for the k-permuted loads ----
    const int off0 = q * HWSZ + colc;        // ch q        (j=0)
    const int off1 = (4 + q) * HWSZ + colc;  // ch 4+q      (j=1)
    const int off2 = 8 * HWSZ + colc;        // ch 8 (q==0) (j=2)
    const float j2fill = (q == 1) ? 1.f : 0.f;  // bias / zero for j=2

    // ---- double-buffered raw input regs: [j] for rows (r, r+1) ----
    float ca[3], cb[3], na[3], nb[3];

    auto LOAD = [&](int r, float (&v0)[3], float (&v1)[3]) {
        const float* rbase = in + (size_t)r * WW;   // wave-uniform base
        v0[0] = rbase[off0]; v1[0] = rbase[off0 + WW];
        v0[1] = rbase[off1]; v1[1] = rbase[off1 + WW];
        float x0 = j2fill, x1 = j2fill;
        if (q == 0) { x0 = rbase[off2]; x1 = rbase[off2 + WW]; }
        v0[2] = x0; v1[2] = x1;
    };

    // relu + pack helper
    auto maxpk = [&](float x, float y) {
        return __builtin_elementwise_max(__builtin_amdgcn_cvt_pkrtz(x, y), z2);
    };

    auto COMPUTE = [&](int it, const float (&v0)[3], const float (&v1)[3]) {
        // ---- pack inputs to f16 (k-permuted layout; e4..e7 = 0) ----
        U8 b0u, b1u;
        b0u.h[0] = __builtin_amdgcn_cvt_pkrtz(v0[0], v0[1]);
        b0u.h[1] = __builtin_amdgcn_cvt_pkrtz(v0[2], 0.f);
        b0u.h[2] = z2; b0u.h[3] = z2;
        b1u.h[0] = __builtin_amdgcn_cvt_pkrtz(v1[0], v1[1]);
        b1u.h[1] = __builtin_amdgcn_cvt_pkrtz(v1[2], 0.f);
        b1u.h[2] = z2; b1u.h[3] = z2;

        // ---- layer 1 ----
        f32x4 D1a[2], D1b[2];
#pragma unroll
        for (int t = 0; t < 2; ++t) {
            D1a[t] = __builtin_amdgcn_mfma_f32_16x16x32_f16(A1[t], b0u.v, zf4, 0, 0, 0);
            D1b[t] = __builtin_amdgcn_mfma_f32_16x16x32_f16(A1[t], b1u.v, zf4, 0, 0, 0);
        }

        // ---- L1 epilogue -> B2 in registers (zero data movement) ----
        // lane(g,px): P0=(ch4g,4g+1), P1=(4g+2,4g+3), Q0=(ch16+4g,17+4g)
        // (Q0 is (ch16,17) in g0, zeros in g1-3 since A1 rows >=18 are 0).
        U8 B2a, B2b;
        B2a.h[0] = maxpk(D1a[0][0], D1a[0][1]);
        B2a.h[1] = maxpk(D1a[0][2], D1a[0][3]);
        B2a.h[2] = maxpk(D1a[1][0], D1a[1][1]);
        B2a.h[3] = cB;
        B2b.h[0] = maxpk(D1b[0][0], D1b[0][1]);
        B2b.h[1] = maxpk(D1b[0][2], D1b[0][3]);
        B2b.h[2] = maxpk(D1b[1][0], D1b[1][1]);
        B2b.h[3] = cB;

        // ---- layer 2 ----
        f32x4 D2a[3], D2b[3];
#pragma unroll
        for (int t = 0; t < 3; ++t) {
            D2a[t] = __builtin_amdgcn_mfma_f32_16x16x32_f16(A2[t], B2a.v, zf4, 0, 0, 0);
            D2b[t] = __builtin_amdgcn_mfma_f32_16x16x32_f16(A2[t], B2b.v, zf4, 0, 0, 0);
        }

        // ---- L2 epilogue -> B3 slices in registers ----
        U8 B3a0, B3b0, B3a1, B3b1;
        B3a0.h[0] = maxpk(D2a[0][0], D2a[0][1]);
        B3a0.h[1] = maxpk(D2a[0][2], D2a[0][3]);
        B3a0.h[2] = maxpk(D2a[1][0], D2a[1][1]);
        B3a0.h[3] = maxpk(D2a[1][2], D2a[1][3]);
        B3a1.h[0] = maxpk(D2a[2][0], D2a[2][1]);
        B3a1.h[1] = maxpk(D2a[2][2], D2a[2][3]);
        B3a1.h[2] = cB;
        B3a1.h[3] = z2;
        B3b0.h[0] = maxpk(D2b[0][0], D2b[0][1]);
        B3b0.h[1] = maxpk(D2b[0][2], D2b[0][3]);
        B3b0.h[2] = maxpk(D2b[1][0], D2b[1][1]);
        B3b0.h[3] = maxpk(D2b[1][2], D2b[1][3]);
        B3b1.h[0] = maxpk(D2b[2][0], D2b[2][1]);
        B3b1.h[1] = maxpk(D2b[2][2], D2b[2][3]);
        B3b1.h[2] = cB;
        B3b1.h[3] = z2;

        // ---- layer 3 (two K-slices) ----
        f32x4 D3a[3], D3b[3];
#pragma unroll
        for (int t = 0; t < 3; ++t) {
            D3a[t] = __builtin_amdgcn_mfma_f32_16x16x32_f16(A3s0[t], B3a0.v, zf4, 0, 0, 0);
            D3a[t] = __builtin_amdgcn_mfma_f32_16x16x32_f16(A3s1[t], B3a1.v, D3a[t], 0, 0, 0);
            D3b[t] = __builtin_amdgcn_mfma_f32_16x16x32_f16(A3s0[t], B3b0.v, zf4, 0, 0, 0);
            D3b[t] = __builtin_amdgcn_mfma_f32_16x16x32_f16(A3s1[t], B3b1.v, D3b[t], 0, 0, 0);
        }

        // ---- layer 4: packed relu + v_dot2_f32_f16, then 2 sum-shuffles ----
        float sa0 = 0.f, sa1 = 0.f, sb0 = 0.f, sb1 = 0.f;
#pragma unroll
        for (int t = 0; t < 3; ++t) {
            sa0 = __builtin_amdgcn_fdot2(maxpk(D3a[t][0], D3a[t][1]), w4p[t][0], sa0, false);
            sa1 = __builtin_amdgcn_fdot2(maxpk(D3a[t][2], D3a[t][3]), w4p[t][1], sa1, false);
            sb0 = __builtin_amdgcn_fdot2(maxpk(D3b[t][0], D3b[t][1]), w4p[t][0], sb0, false);
            sb1 = __builtin_amdgcn_fdot2(maxpk(D3b[t][2], D3b[t][3]), w4p[t][1], sb1, false);
        }
        float sa = sa0 + sa1;
        float sb = sb0 + sb1;
        sa += __shfl_xor(sa, 16, 64); sb += __shfl_xor(sb, 16, 64);
        sa += __shfl_xor(sa, 32, 64); sb += __shfl_xor(sb, 32, 64);
        sa += b4s; sb += b4s;

        sa = colok ? sa : NEG_INF;
        sb = colok ? sb : NEG_INF;
        colmax = fmaxf(colmax, fmaxf(sa, sb));

        // every lane holds the full s(px); scatter to [row][px].
        if (q == 0) rowsm[wv][it * 2][px] = sa;
        else if (q == 1) rowsm[wv][it * 2 + 1][px] = sb;
    };

    // ---- main loop: 8 iterations (16 rows), depth-1 ping-pong prefetch ----
    LOAD(rb, ca, cb);
#pragma unroll 1
    for (int it = 0; it < 8; it += 2) {
        LOAD(rb + (it + 1) * 2, na, nb);   // prefetch odd half-step
        COMPUTE(it, ca, cb);
        if (it < 6) LOAD(rb + (it + 2) * 2, ca, cb);  // prefetch next even
        COMPUTE(it + 1, na, nb);
    }

    // ---- end-of-wave flush (no barrier: rowsm slice is wave-private) ----
    if (q == 0 && colok) atomicMax(&colbuck[col], fenc(colmax));
    if (tx < 16) {
        const f32x4 v0 = *(const f32x4*)&rowsm[wv][tx][0];
        const f32x4 v1 = *(const f32x4*)&rowsm[wv][tx][4];
        const f32x4 v2 = *(const f32x4*)&rowsm[wv][tx][8];
        const f32x4 v3 = *(const f32x4*)&rowsm[wv][tx][12];
        float m = NEG_INF;
#pragma unroll
        for (int j = 0; j < 4; ++j) {
            m = fmaxf(m, fmaxf(fmaxf(v0[j], v1[j]), fmaxf(v2[j], v3[j])));
        }
        atomicMax(&rowbuck[rb + tx], fenc(m));
    }
}

extern "C" void kernel_launch(void* const* d_in, const int* in_sizes, int n_in,
                              void* d_out, int out_size, void* d_ws, size_t ws_size,
                              hipStream_t stream) {
    const float* in = (const float*)d_in[0];
    // d_in[1] = T_out (unused), d_in[2] = T_indices (identity, unused)
    const float* w1 = (const float*)d_in[3];
    const float* b1 = (const float*)d_in[4];
    const float* w2 = (const float*)d_in[5];
    const float* b2 = (const float*)d_in[6];
    const float* w3 = (const float*)d_in[7];
    const float* b3 = (const float*)d_in[8];
    const float* w4 = (const float*)d_in[9];
    const float* b4 = (const float*)d_in[10];

    unsigned* buck = (unsigned*)d_out;  // [0,2000) row maxes, [2000,3000) col maxes

    // fenc never produces 0, so memset-0 is a valid atomicMax identity.
    (void)hipMemsetAsync(buck, 0, 3000 * sizeof(unsigned), stream);

    dim3 block(64, 2);
    dim3 grid(32, 125);  // 32*32=1024 >= 1000 cols ; 125*16=2000 rows exactly
    mlp_max_mfma<<<grid, block, 0, stream>>>(in, w1, b1, w2, b2, w3, b3, w4, b4,
                                             buck, buck + 2000);

    decode_buckets<<<(3000 + 255) / 256, 256, 0, stream>>>(buck, 3000);
}

// Round 11
// 171.825 us; speedup vs baseline: 1.1981x; 1.0190x over previous
//
#include <hip/hip_runtime.h>

typedef _Float16 f16x8 __attribute__((ext_vector_type(8)));
typedef _Float16 f16x4 __attribute__((ext_vector_type(4)));
typedef __fp16 h16x2 __attribute__((ext_vector_type(2)));  // cvt_pkrtz native type
typedef float f32x4 __attribute__((ext_vector_type(4)));

#define HH 2000
#define WW 1000
#define HWSZ (HH * WW)
#define NEG_INF (-3.0e38f)

// ---- monotone float<->uint encoding for atomicMax on floats ----
// fenc never returns 0, so buckets are initialized with plain memset(0).
__device__ __forceinline__ unsigned fenc(float f) {
    unsigned u = __float_as_uint(f);
    return (u & 0x80000000u) ? ~u : (u | 0x80000000u);
}
__device__ __forceinline__ float fdec(unsigned k) {
    unsigned u = (k & 0x80000000u) ? (k & 0x7fffffffu) : ~k;
    return __uint_as_float(u);
}

__global__ void decode_buckets(unsigned* __restrict__ buck, int n) {
    int i = blockIdx.x * blockDim.x + threadIdx.x;
    if (i < n) {
        unsigned k = buck[i];
        ((float*)buck)[i] = fdec(k);
    }
}

// MFMA 16x16x32 f16 layouts (gfx950, verified: absmax ~2e-3):
//   A: lane holds A[m=lane&15][k=(lane>>4)*8+j]
//   B: lane holds B[k=(lane>>4)*8+j][n=lane&15]
//   D: lane holds D[row=(lane>>4)*4+reg][col=lane&15]
//
// R24 = R23 (zero-LDS layer transitions; 66us, bank-conflicts 3.3M->64K
// confirmed the DS-chain theory) + L4-as-MFMA:
// The relu-packed D3 outputs already form a B fragment with EXACTLY A3s0's
// k-map shape: {pk0_0,pk1_0,pk0_1,pk1_1} <-> ch 4g+j / 16+4g+(j-4); slice1
// {pk0_2,pk1_2,cB,0} covers ch32-35 + bias (g>=1 packs are zeros since
// A3 rows >=36 are zero). A4 = w4 in row m=0 (px==0 lanes only), b4 folded
// into slice1's bias slot. Two chained MFMAs/row yield s(px)+b4 in lane
// (0,px) reg0 -- replacing 12 fdot2 + 4 dependent ds_bpermute shuffles +
// bias/mask VALU. Remaining DS/iter: 2 conflict-free rowsm writes.
// OOB-col masking dropped from the loop: clamped duplicate cols cannot
// change a row max; colbuck flush masks by colok as before.

__global__ __launch_bounds__(128) void mlp_max_mfma(
    const float* __restrict__ in,
    const float* __restrict__ w1, const float* __restrict__ b1,
    const float* __restrict__ w2, const float* __restrict__ b2,
    const float* __restrict__ w3, const float* __restrict__ b3,
    const float* __restrict__ w4, const float* __restrict__ b4,
    unsigned* __restrict__ rowbuck, unsigned* __restrict__ colbuck) {
    __shared__ float rowsm[2][16][16];   // [wave][row-in-block][px]

    const int tx = threadIdx.x;   // 0..63
    const int wv = threadIdx.y;   // 0..1 (independent waves)
    const int px = tx & 15;
    const int q = tx >> 4;        // lane group g

    // ---- weight A-fragments (persistent; k-maps documented above) ----
    f16x8 A1[2], A2[3], A3s0[3], A3s1[3], A4s0, A4s1;
    // L1 (R22-verified k-map): j0 -> ch q ; j1 -> ch 4+q ; j2 -> (q0: ch8,
    // q1: bias); j>=3 zero.
#pragma unroll
    for (int t = 0; t < 2; ++t) {
        const int m = t * 16 + px;
#pragma unroll
        for (int j = 0; j < 8; ++j) {
            float v = 0.f;
            if (m < 18) {
                if (j == 0) v = w1[m * 9 + q];
                else if (j == 1) v = w1[m * 9 + 4 + q];
                else if (j == 2) {
                    if (q == 0) v = w1[m * 9 + 8];
                    else if (q == 1) v = b1[m];
                }
            }
            A1[t][j] = (_Float16)v;
        }
    }
    // L2: k=8q+j <-> ch 4q+j (j<4); q0: j4->ch16, j5->ch17, j6->bias.
#pragma unroll
    for (int t = 0; t < 3; ++t) {
        const int m = t * 16 + px;
#pragma unroll
        for (int j = 0; j < 8; ++j) {
            float v = 0.f;
            if (m < 36) {
                if (j < 4) v = w2[m * 18 + 4 * q + j];
                else if (q == 0) {
                    if (j == 4) v = w2[m * 18 + 16];
                    else if (j == 5) v = w2[m * 18 + 17];
                    else if (j == 6) v = b2[m];
                }
            }
            A2[t][j] = (_Float16)v;
        }
    }
    // L3 slice0: k=8q+j <-> ch 4q+j (j<4), ch 16+4q+(j-4) (j>=4).
    // L3 slice1: q0 j0-3 -> ch 32..35 ; q0 j4 -> bias ; else 0.
#pragma unroll
    for (int t = 0; t < 3; ++t) {
        const int m = t * 16 + px;
#pragma unroll
        for (int j = 0; j < 8; ++j) {
            float v = 0.f;
            if (m < 36) {
                const int ch = (j < 4) ? (4 * q + j) : (16 + 4 * q + (j - 4));
                v = w3[m * 36 + ch];
            }
            A3s0[t][j] = (_Float16)v;
            float v2 = 0.f;
            if (m < 36 && q == 0) {
                if (j < 4) v2 = w3[m * 36 + 32 + j];
                else if (j == 4) v2 = b3[m];
            }
            A3s1[t][j] = (_Float16)v2;
        }
    }
    // L4: same k-maps as L3 slices, but only row m=0 (px==0 lanes) nonzero.
#pragma unroll
    for (int j = 0; j < 8; ++j) {
        float v = 0.f, v2 = 0.f;
        if (px == 0) {
            const int ch = (j < 4) ? (4 * q + j) : (16 + 4 * q + (j - 4));
            v = w4[ch];
            if (q == 0) {
                if (j < 4) v2 = w4[32 + j];
                else if (j == 4) v2 = b4[0];
            }
        }
        A4s0[j] = (_Float16)v;
        A4s1[j] = (_Float16)v2;
    }

    const int col = blockIdx.x * 32 + wv * 16 + px;
    const int colc = (col < WW) ? col : (WW - 1);
    const bool colok = (col < WW);
    const int rb = blockIdx.y * 16;

    float colmax = NEG_INF;
    const f32x4 zf4 = {0.f, 0.f, 0.f, 0.f};
    const h16x2 z2 = {(__fp16)0.f, (__fp16)0.f};
    // loop-invariant bias-channel constants (g0 carries (1.0, 0))
    const h16x2 cB = (q == 0) ? __builtin_amdgcn_cvt_pkrtz(1.f, 0.f) : z2;

    union U8 { f16x8 v; h16x2 h[4]; };

    // ---- per-lane 32-bit element offsets for the k-permuted loads ----
    const int off0 = q * HWSZ + colc;        // ch q        (j=0)
    const int off1 = (4 + q) * HWSZ + colc;  // ch 4+q      (j=1)
    const int off2 = 8 * HWSZ + colc;        // ch 8 (q==0) (j=2)
    const float j2fill = (q == 1) ? 1.f : 0.f;  // bias / zero for j=2

    // ---- double-buffered raw input regs: [j] for rows (r, r+1) ----
    float ca[3], cb[3], na[3], nb[3];

    auto LOAD = [&](int r, float (&v0)[3], float (&v1)[3]) {
        const float* rbase = in + (size_t)r * WW;   // wave-uniform base
        v0[0] = rbase[off0]; v1[0] = rbase[off0 + WW];
        v0[1] = rbase[off1]; v1[1] = rbase[off1 + WW];
        float x0 = j2fill, x1 = j2fill;
        if (q == 0) { x0 = rbase[off2]; x1 = rbase[off2 + WW]; }
        v0[2] = x0; v1[2] = x1;
    };

    // relu + pack helper
    auto maxpk = [&](float x, float y) {
        return __builtin_elementwise_max(__builtin_amdgcn_cvt_pkrtz(x, y), z2);
    };

    auto COMPUTE = [&](int it, const float (&v0)[3], const float (&v1)[3]) {
        // ---- pack inputs to f16 (k-permuted layout; e4..e7 = 0) ----
        U8 b0u, b1u;
        b0u.h[0] = __builtin_amdgcn_cvt_pkrtz(v0[0], v0[1]);
        b0u.h[1] = __builtin_amdgcn_cvt_pkrtz(v0[2], 0.f);
        b0u.h[2] = z2; b0u.h[3] = z2;
        b1u.h[0] = __builtin_amdgcn_cvt_pkrtz(v1[0], v1[1]);
        b1u.h[1] = __builtin_amdgcn_cvt_pkrtz(v1[2], 0.f);
        b1u.h[2] = z2; b1u.h[3] = z2;

        // ---- layer 1 ----
        f32x4 D1a[2], D1b[2];
#pragma unroll
        for (int t = 0; t < 2; ++t) {
            D1a[t] = __builtin_amdgcn_mfma_f32_16x16x32_f16(A1[t], b0u.v, zf4, 0, 0, 0);
            D1b[t] = __builtin_amdgcn_mfma_f32_16x16x32_f16(A1[t], b1u.v, zf4, 0, 0, 0);
        }

        // ---- L1 epilogue -> B2 in registers (zero data movement) ----
        U8 B2a, B2b;
        B2a.h[0] = maxpk(D1a[0][0], D1a[0][1]);
        B2a.h[1] = maxpk(D1a[0][2], D1a[0][3]);
        B2a.h[2] = maxpk(D1a[1][0], D1a[1][1]);
        B2a.h[3] = cB;
        B2b.h[0] = maxpk(D1b[0][0], D1b[0][1]);
        B2b.h[1] = maxpk(D1b[0][2], D1b[0][3]);
        B2b.h[2] = maxpk(D1b[1][0], D1b[1][1]);
        B2b.h[3] = cB;

        // ---- layer 2 ----
        f32x4 D2a[3], D2b[3];
#pragma unroll
        for (int t = 0; t < 3; ++t) {
            D2a[t] = __builtin_amdgcn_mfma_f32_16x16x32_f16(A2[t], B2a.v, zf4, 0, 0, 0);
            D2b[t] = __builtin_amdgcn_mfma_f32_16x16x32_f16(A2[t], B2b.v, zf4, 0, 0, 0);
        }

        // ---- L2 epilogue -> B3 slices in registers ----
        U8 B3a0, B3b0, B3a1, B3b1;
        B3a0.h[0] = maxpk(D2a[0][0], D2a[0][1]);
        B3a0.h[1] = maxpk(D2a[0][2], D2a[0][3]);
        B3a0.h[2] = maxpk(D2a[1][0], D2a[1][1]);
        B3a0.h[3] = maxpk(D2a[1][2], D2a[1][3]);
        B3a1.h[0] = maxpk(D2a[2][0], D2a[2][1]);
        B3a1.h[1] = maxpk(D2a[2][2], D2a[2][3]);
        B3a1.h[2] = cB;
        B3a1.h[3] = z2;
        B3b0.h[0] = maxpk(D2b[0][0], D2b[0][1]);
        B3b0.h[1] = maxpk(D2b[0][2], D2b[0][3]);
        B3b0.h[2] = maxpk(D2b[1][0], D2b[1][1]);
        B3b0.h[3] = maxpk(D2b[1][2], D2b[1][3]);
        B3b1.h[0] = maxpk(D2b[2][0], D2b[2][1]);
        B3b1.h[1] = maxpk(D2b[2][2], D2b[2][3]);
        B3b1.h[2] = cB;
        B3b1.h[3] = z2;

        // ---- layer 3 (two K-slices) ----
        f32x4 D3a[3], D3b[3];
#pragma unroll
        for (int t = 0; t < 3; ++t) {
            D3a[t] = __builtin_amdgcn_mfma_f32_16x16x32_f16(A3s0[t], B3a0.v, zf4, 0, 0, 0);
            D3a[t] = __builtin_amdgcn_mfma_f32_16x16x32_f16(A3s1[t], B3a1.v, D3a[t], 0, 0, 0);
            D3b[t] = __builtin_amdgcn_mfma_f32_16x16x32_f16(A3s0[t], B3b0.v, zf4, 0, 0, 0);
            D3b[t] = __builtin_amdgcn_mfma_f32_16x16x32_f16(A3s1[t], B3b1.v, D3b[t], 0, 0, 0);
        }

        // ---- L3 epilogue -> B4 slices (same pattern as B3) ----
        U8 B4a0, B4b0, B4a1, B4b1;
        B4a0.h[0] = maxpk(D3a[0][0], D3a[0][1]);
        B4a0.h[1] = maxpk(D3a[0][2], D3a[0][3]);
        B4a0.h[2] = maxpk(D3a[1][0], D3a[1][1]);
        B4a0.h[3] = maxpk(D3a[1][2], D3a[1][3]);
        B4a1.h[0] = maxpk(D3a[2][0], D3a[2][1]);
        B4a1.h[1] = maxpk(D3a[2][2], D3a[2][3]);
        B4a1.h[2] = cB;
        B4a1.h[3] = z2;
        B4b0.h[0] = maxpk(D3b[0][0], D3b[0][1]);
        B4b0.h[1] = maxpk(D3b[0][2], D3b[0][3]);
        B4b0.h[2] = maxpk(D3b[1][0], D3b[1][1]);
        B4b0.h[3] = maxpk(D3b[1][2], D3b[1][3]);
        B4b1.h[0] = maxpk(D3b[2][0], D3b[2][1]);
        B4b1.h[1] = maxpk(D3b[2][2], D3b[2][3]);
        B4b1.h[2] = cB;
        B4b1.h[3] = z2;

        // ---- layer 4 as MFMA: s(px)+b4 lands in lane (0,px) reg 0 ----
        f32x4 D4a = __builtin_amdgcn_mfma_f32_16x16x32_f16(A4s0, B4a0.v, zf4, 0, 0, 0);
        D4a = __builtin_amdgcn_mfma_f32_16x16x32_f16(A4s1, B4a1.v, D4a, 0, 0, 0);
        f32x4 D4b = __builtin_amdgcn_mfma_f32_16x16x32_f16(A4s0, B4b0.v, zf4, 0, 0, 0);
        D4b = __builtin_amdgcn_mfma_f32_16x16x32_f16(A4s1, B4b1.v, D4b, 0, 0, 0);

        const float sa = D4a[0];
        const float sb = D4b[0];
        // q==0 lanes hold the真 result; other lanes hold zeros (A4 rows>0 = 0)
        colmax = fmaxf(colmax, fmaxf(sa, sb));
        if (q == 0) {
            rowsm[wv][it * 2][px] = sa;
            rowsm[wv][it * 2 + 1][px] = sb;
        }
    };

    // ---- main loop: 8 iterations (16 rows), depth-1 ping-pong prefetch ----
    LOAD(rb, ca, cb);
#pragma unroll 1
    for (int it = 0; it < 8; it += 2) {
        LOAD(rb + (it + 1) * 2, na, nb);   // prefetch odd half-step
        COMPUTE(it, ca, cb);
        if (it < 6) LOAD(rb + (it + 2) * 2, ca, cb);  // prefetch next even
        COMPUTE(it + 1, na, nb);
    }

    // ---- end-of-wave flush (no barrier: rowsm slice is wave-private) ----
    if (q == 0 && colok) atomicMax(&colbuck[col], fenc(colmax));
    if (tx < 16) {
        const f32x4 v0 = *(const f32x4*)&rowsm[wv][tx][0];
        const f32x4 v1 = *(const f32x4*)&rowsm[wv][tx][4];
        const f32x4 v2 = *(const f32x4*)&rowsm[wv][tx][8];
        const f32x4 v3 = *(const f32x4*)&rowsm[wv][tx][12];
        float m = NEG_INF;
#pragma unroll
        for (int j = 0; j < 4; ++j) {
            m = fmaxf(m, fmaxf(fmaxf(v0[j], v1[j]), fmaxf(v2[j], v3[j])));
        }
        atomicMax(&rowbuck[rb + tx], fenc(m));
    }
}

extern "C" void kernel_launch(void* const* d_in, const int* in_sizes, int n_in,
                              void* d_out, int out_size, void* d_ws, size_t ws_size,
                              hipStream_t stream) {
    const float* in = (const float*)d_in[0];
    // d_in[1] = T_out (unused), d_in[2] = T_indices (identity, unused)
    const float* w1 = (const float*)d_in[3];
    const float* b1 = (const float*)d_in[4];
    const float* w2 = (const float*)d_in[5];
    const float* b2 = (const float*)d_in[6];
    const float* w3 = (const float*)d_in[7];
    const float* b3 = (const float*)d_in[8];
    const float* w4 = (const float*)d_in[9];
    const float* b4 = (const float*)d_in[10];

    unsigned* buck = (unsigned*)d_out;  // [0,2000) row maxes, [2000,3000) col maxes

    // fenc never produces 0, so memset-0 is a valid atomicMax identity.
    (void)hipMemsetAsync(buck, 0, 3000 * sizeof(unsigned), stream);

    dim3 block(64, 2);
    dim3 grid(32, 125);  // 32*32=1024 >= 1000 cols ; 125*16=2000 rows exactly
    mlp_max_mfma<<<grid, block, 0, stream>>>(in, w1, b1, w2, b2, w3, b3, w4, b4,
                                             buck, buck + 2000);

    decode_buckets<<<(3000 + 255) / 256, 256, 0, stream>>>(buck, 3000);
}